// Round 26
// baseline (156.152 us; speedup 1.0000x reference)
//
#include <hip/hip_runtime.h>
#include <stdint.h>

typedef float  f32x4  __attribute__((ext_vector_type(4)));
typedef short  s16x4  __attribute__((ext_vector_type(4)));
typedef short  s16x8  __attribute__((ext_vector_type(8)));

#define S_LEN 2048
#define D_K   64
#define NBH   32
#define VT_STRIDE (S_LEN + 32)
#define MFMA  __builtin_amdgcn_mfma_f32_16x16x32_bf16

__device__ __forceinline__ short f2bf(float f) {
    uint32_t u = __builtin_bit_cast(uint32_t, f);
    u += 0x7fffu + ((u >> 16) & 1u);           // RNE
    return (short)(u >> 16);
}
__device__ __forceinline__ float bf2f(short s) {
    uint32_t u = ((uint32_t)(uint16_t)s) << 16;
    return __builtin_bit_cast(float, u);
}
__device__ __forceinline__ s16x4 cvt4(float4 f) {
    s16x4 r; r[0] = f2bf(f.x); r[1] = f2bf(f.y); r[2] = f2bf(f.z); r[3] = f2bf(f.w);
    return r;
}
__device__ __forceinline__ s16x8 cat(s16x4 a, s16x4 b) {
    return __builtin_shufflevector(a, b, 0, 1, 2, 3, 4, 5, 6, 7);
}
__device__ __forceinline__ void nt_store4(float* p, f32x4 v) {
    __builtin_nontemporal_store(v, (f32x4*)p);
}

// ---- pre-pass: K -> bf16 FRAG-PERMUTED rows, V -> bf16 transposed, k-permuted ----
__global__ __launch_bounds__(256) void preconv(
    const float* __restrict__ K, const float* __restrict__ V,
    short* __restrict__ Kb, short* __restrict__ VT)
{
    const int bh  = blockIdx.x >> 6;
    const int seg = blockIdx.x & 63;
    const int tid = threadIdx.x;
    const float* Ks = K + ((size_t)bh * S_LEN + seg * 32) * D_K;
    const float* Vs = V + ((size_t)bh * S_LEN + seg * 32) * D_K;
    short* Kd  = Kb + ((size_t)bh * S_LEN + seg * 32) * D_K;
    short* VTd = VT + (size_t)bh * D_K * VT_STRIDE + seg * 32;

    for (int i = tid; i < 512; i += 256) {
        const int r = i >> 4, ci = i & 15;
        float4 f = *(const float4*)(Ks + r * D_K + (ci << 2));
        const int jj = ((ci & 3) << 1) + ((ci >> 2) & 1) + ((ci >> 3) << 3);
        *(s16x4*)(Kd + r * D_K + (jj << 2)) = cvt4(f);
    }
    for (int i = tid; i < 512; i += 256) {
        const int r = i & 31, c = (i >> 5) << 2;
        float4 f = *(const float4*)(Vs + r * D_K + c);
        const int rp = (((r & 15) >> 2) << 3) + (((r >> 4) & 1) << 2) + (r & 3);
        VTd[(size_t)(c + 0) * VT_STRIDE + rp] = f2bf(f.x);
        VTd[(size_t)(c + 1) * VT_STRIDE + rp] = f2bf(f.y);
        VTd[(size_t)(c + 2) * VT_STRIDE + rp] = f2bf(f.z);
        VTd[(size_t)(c + 3) * VT_STRIDE + rp] = f2bf(f.w);
    }
}

// ---- single-pass SINGLE-STRIP kernel (66KB LDS -> 2 blocks/CU so one block's
// ---- flush overlaps the other's compute): ONE QK^T pass; bf16 exp stash;
// ---- unnormalized PV; 8KB/row mega-flush with fused zero-fill ----
#define SSTR 2056    // shorts per stash row (2048 + 8 pad)
__global__ __launch_bounds__(256) void attn_ss(
    const float* __restrict__ Q, const short* __restrict__ Kb,
    const short* __restrict__ VT, float* __restrict__ outC,
    float* __restrict__ outS)
{
    __shared__ __align__(16) char smem[16 * SSTR * 2];   // 65.8 KB stash / combine
    __shared__ float lbuf[4][16];

    const int tid = threadIdx.x, lane = tid & 63, wv = tid >> 6;
    const int xcd = blockIdx.x & 7;
    const int idx = blockIdx.x >> 3;             // 0..511
    const int bh  = (xcd << 2) + (idx >> 7);     // 0..31
    const int strip = 127 - (idx & 127);         // heavy strips first
    const int q0  = strip << 4;                  // 16 rows
    const int l15 = lane & 15;
    const int g   = lane >> 4;
    const int d0  = g << 2;
    const int qg  = q0 + l15;

    const short* Kbh = Kb + (size_t)bh * S_LEN * D_K;
    const short* VTh = VT + (size_t)bh * D_K * VT_STRIDE;
    float* outSb = outS + (size_t)bh * S_LEN * S_LEN;
    float* outCb = outC + (size_t)bh * S_LEN * D_K;
    short* sstash = (short*)smem;

    s16x8 qf0, qf1;
    {
        const float4* qp = (const float4*)(Q + ((size_t)bh * S_LEN + qg) * D_K);
        qf0 = cat(cvt4(qp[g]),     cvt4(qp[g + 4]));
        qf1 = cat(cvt4(qp[g + 8]), cvt4(qp[g + 12]));
    }

    const int ntiles = (strip >> 1) + 1;
    const int nfull  = strip >> 1;
    const float scale = 0.125f;

    // ============ single pass: QK^T -> exp (unnorm) -> stash + sums + PV ============
    float lsum = 0.f;
    f32x4 z4 = {0.f,0.f,0.f,0.f};
    f32x4 cx0 = z4, cx1 = z4, cx2 = z4, cx3 = z4;
    {
        s16x8 k0[4], v0[4], k1[4], v1[4];

        auto LDK = [&](s16x8* kk, s16x8* vv, int t) {
            const short* kp = Kbh + (((size_t)t << 5) + l15) * D_K + (g << 3);
            kk[0] = *(const s16x8*)(kp);
            kk[1] = *(const s16x8*)(kp + 32);
            kk[2] = *(const s16x8*)(kp + 16 * D_K);
            kk[3] = *(const s16x8*)(kp + 16 * D_K + 32);
            const short* vp = VTh + (size_t)l15 * VT_STRIDE + (t << 5) + (g << 3);
            vv[0] = *(const s16x8*)(vp);
            vv[1] = *(const s16x8*)(vp + 16 * VT_STRIDE);
            vv[2] = *(const s16x8*)(vp + 32 * VT_STRIDE);
            vv[3] = *(const s16x8*)(vp + 48 * VT_STRIDE);
        };
        auto CMPS = [&](const s16x8* kk, const s16x8* vv, int T) {
            f32x4 s0 = z4, s1 = z4;
            s0 = MFMA(kk[0], qf0, s0, 0,0,0);
            s0 = MFMA(kk[1], qf1, s0, 0,0,0);
            s1 = MFMA(kk[2], qf0, s1, 0,0,0);
            s1 = MFMA(kk[3], qf1, s1, 0,0,0);
            s16x8 pf;
            if (T < nfull) {
                #pragma unroll
                for (int r = 0; r < 4; ++r) {
                    float e;
                    e = __expf(s0[r] * scale); lsum += e; pf[r]   = f2bf(e);
                    e = __expf(s1[r] * scale); lsum += e; pf[4+r] = f2bf(e);
                }
            } else {      // diagonal tile (R16-proven general condition)
                const int kb0 = (T << 5) + d0;
                #pragma unroll
                for (int r = 0; r < 4; ++r) {
                    float e;
                    e = (kb0 + r <= qg)      ? __expf(s0[r] * scale) : 0.f;
                    lsum += e; pf[r] = f2bf(e);
                    e = (kb0 + 16 + r <= qg) ? __expf(s1[r] * scale) : 0.f;
                    lsum += e; pf[4+r] = f2bf(e);
                }
            }
            // stash bf16 exp (unnormalized); wave-private tiles, no barrier needed
            const int cbase = (T << 5) + d0;
            short* sA = &sstash[l15 * SSTR + cbase];
            *(s16x4*)(sA)      = __builtin_shufflevector(pf, pf, 0, 1, 2, 3);
            *(s16x4*)(sA + 16) = __builtin_shufflevector(pf, pf, 4, 5, 6, 7);
            cx0 = MFMA(pf, vv[0], cx0, 0,0,0);
            cx1 = MFMA(pf, vv[1], cx1, 0,0,0);
            cx2 = MFMA(pf, vv[2], cx2, 0,0,0);
            cx3 = MFMA(pf, vv[3], cx3, 0,0,0);
        };

        int t = wv;
        if (t < ntiles) {
            LDK(k0, v0, t);
            while (t + 4 < ntiles) {
                LDK(k1, v1, t + 4);
                CMPS(k0, v0, t);
                t += 4;
                if (t + 4 < ntiles) {
                    LDK(k0, v0, t + 4);
                    CMPS(k1, v1, t);
                    t += 4;
                } else {
                    CMPS(k1, v1, t);
                    t += 4;
                    break;
                }
            }
            if (t < ntiles) CMPS(k0, v0, t);
        }
    }
    lsum += __shfl_xor(lsum, 16);
    lsum += __shfl_xor(lsum, 32);
    if (lane < 16) lbuf[wv][l15] = lsum;
    __syncthreads();
    // ctx accumulator row is d0+r (C/D layout)
    #pragma unroll
    for (int r = 0; r < 4; ++r) {
        const float ra = 1.f / (lbuf[0][d0 + r] + lbuf[1][d0 + r]
                              + lbuf[2][d0 + r] + lbuf[3][d0 + r]);
        cx0[r] *= ra; cx1[r] *= ra; cx2[r] *= ra; cx3[r] *= ra;
    }

    // ============ mega-flush: each row one 8KB sequential run (P + zeros) ============
    const int kz = ntiles << 5;
    {
        #pragma unroll
        for (int rr4 = 0; rr4 < 4; ++rr4) {
            const int row = (wv << 2) + rr4;     // 0..15
            const float rinv_r = 1.f /
                (lbuf[0][row] + lbuf[1][row] + lbuf[2][row] + lbuf[3][row]);
            float* rowp = outSb + (size_t)(q0 + row) * S_LEN;
            const short* srow = &sstash[row * SSTR];
            for (int c = lane << 2; c < S_LEN; c += 256) {
                f32x4 v;
                if (c < kz) {
                    s16x4 sv = *(const s16x4*)(srow + c);
                    v[0] = bf2f(sv[0]) * rinv_r;
                    v[1] = bf2f(sv[1]) * rinv_r;
                    v[2] = bf2f(sv[2]) * rinv_r;
                    v[3] = bf2f(sv[3]) * rinv_r;
                } else {
                    v[0] = 0.f; v[1] = 0.f; v[2] = 0.f; v[3] = 0.f;
                }
                nt_store4(rowp + c, v);
            }
        }
    }

    // ============ ctx combine (reuse stash memory as [4][16][65] f32) ============
    __syncthreads();   // flush reads of stash complete
    {
        float* cb2 = (float*)smem;
        const int base = wv * 1040;              // 16*65
        #pragma unroll
        for (int r = 0; r < 4; ++r) {
            cb2[base + (d0 + r) * 65 +  0 + l15] = cx0[r];
            cb2[base + (d0 + r) * 65 + 16 + l15] = cx1[r];
            cb2[base + (d0 + r) * 65 + 32 + l15] = cx2[r];
            cb2[base + (d0 + r) * 65 + 48 + l15] = cx3[r];
        }
        __syncthreads();
        const int row = tid >> 4, dbase = (tid & 15) << 2;   // 16 rows x 16 thr
        f32x4 acc = *(const f32x4*)&cb2[0 * 1040 + row * 65 + dbase];
        #pragma unroll
        for (int w = 1; w < 4; ++w) {
            f32x4 p = *(const f32x4*)&cb2[w * 1040 + row * 65 + dbase];
            acc[0] += p[0]; acc[1] += p[1]; acc[2] += p[2]; acc[3] += p[3];
        }
        *(f32x4*)(outCb + (size_t)(q0 + row) * D_K + dbase) = acc;
    }
}

// ---------------- fallback (R0 kernel, proven) if ws too small ----------------
#define KSTRIDE 68
#define VSTRIDE 36
__global__ __launch_bounds__(256) void attn_causal_fb(
    const float* __restrict__ Q, const float* __restrict__ K,
    const float* __restrict__ V, float* __restrict__ outC,
    float* __restrict__ outS)
{
    __shared__ short Klds[32 * KSTRIDE];
    __shared__ short Vlds[64 * VSTRIDE];
    const int bh = blockIdx.x >> 5, q0 = (blockIdx.x & 31) << 6;
    const int tid = threadIdx.x, lane = tid & 63, wv = tid >> 6;
    const int q0w = q0 + (wv << 4), l15 = lane & 15, d0 = (lane >> 4) << 2;
    const int qg = q0w + l15, qhi = q0w + 15;
    const float* Kb = K + (size_t)bh * S_LEN * D_K;
    const float* Vb = V + (size_t)bh * S_LEN * D_K;
    float* outSb = outS + (size_t)bh * S_LEN * S_LEN;
    float* outCb = outC + (size_t)bh * S_LEN * D_K;
    s16x8 qf0, qf1;
    {
        const float4* qp = (const float4*)(Q + ((size_t)bh * S_LEN + qg) * D_K);
        qf0 = cat(cvt4(qp[d0 >> 2]), cvt4(qp[(d0 + 16) >> 2]));
        qf1 = cat(cvt4(qp[(d0 + 32) >> 2]), cvt4(qp[(d0 + 48) >> 2]));
    }
    const int npairs = (q0 >> 5) + 2;
    const float scale = 0.125f;
    float lsum = 0.f;
    for (int p = 0; p < npairs; ++p) {
        const int k0 = p << 5;
        for (int i = tid; i < 512; i += 256) {
            const int r = i >> 4, c = (i & 15) << 2;
            float4 f = *(const float4*)(Kb + (size_t)(k0 + r) * D_K + c);
            *(s16x4*)&Klds[r * KSTRIDE + c] = cvt4(f);
        }
        __syncthreads();
        if (k0 <= qhi) {
            #pragma unroll
            for (int s = 0; s < 2; ++s) {
                const short* kp = &Klds[(16 * s + l15) * KSTRIDE + d0];
                s16x8 a0 = cat(*(const s16x4*)kp, *(const s16x4*)(kp + 16));
                s16x8 a1 = cat(*(const s16x4*)(kp + 32), *(const s16x4*)(kp + 48));
                f32x4 c1 = {0.f,0.f,0.f,0.f};
                c1 = MFMA(a0, qf0, c1, 0,0,0);
                c1 = MFMA(a1, qf1, c1, 0,0,0);
                const int kbase = k0 + 16 * s + d0;
                #pragma unroll
                for (int r = 0; r < 4; ++r)
                    if (kbase + r <= qg) lsum += __expf(c1[r] * scale);
            }
        }
        __syncthreads();
    }
    lsum += __shfl_xor(lsum, 16);
    lsum += __shfl_xor(lsum, 32);
    const float rinv = 1.f / lsum;
    f32x4 ctx[4] = {{0,0,0,0},{0,0,0,0},{0,0,0,0},{0,0,0,0}};
    for (int p = 0; p < npairs; ++p) {
        const int k0 = p << 5;
        for (int i = tid; i < 512; i += 256) {
            const int r = i >> 4, c = (i & 15) << 2;
            float4 f = *(const float4*)(Kb + (size_t)(k0 + r) * D_K + c);
            *(s16x4*)&Klds[r * KSTRIDE + c] = cvt4(f);
            float4 gg = *(const float4*)(Vb + (size_t)(k0 + r) * D_K + c);
            Vlds[(c + 0) * VSTRIDE + r] = f2bf(gg.x);
            Vlds[(c + 1) * VSTRIDE + r] = f2bf(gg.y);
            Vlds[(c + 2) * VSTRIDE + r] = f2bf(gg.z);
            Vlds[(c + 3) * VSTRIDE + r] = f2bf(gg.w);
        }
        __syncthreads();
        if (k0 <= qhi) {
            s16x8 pf;
            #pragma unroll
            for (int s = 0; s < 2; ++s) {
                const short* kp = &Klds[(16 * s + l15) * KSTRIDE + d0];
                s16x8 a0 = cat(*(const s16x4*)kp, *(const s16x4*)(kp + 16));
                s16x8 a1 = cat(*(const s16x4*)(kp + 32), *(const s16x4*)(kp + 48));
                f32x4 c1 = {0.f,0.f,0.f,0.f};
                c1 = MFMA(a0, qf0, c1, 0,0,0);
                c1 = MFMA(a1, qf1, c1, 0,0,0);
                const int kbase = k0 + 16 * s + d0;
                f32x4 pw;
                #pragma unroll
                for (int r = 0; r < 4; ++r) {
                    float pe = (kbase + r <= qg) ? __expf(c1[r] * scale) * rinv : 0.f;
                    pw[r] = pe;
                    pf[4 * s + r] = f2bf(pe);
                }
                *(f32x4*)(outSb + (size_t)qg * S_LEN + kbase) = pw;
            }
            #pragma unroll
            for (int db = 0; db < 4; ++db) {
                const short* vp = &Vlds[(db * 16 + l15) * VSTRIDE + d0];
                s16x8 b = cat(*(const s16x4*)vp, *(const s16x4*)(vp + 16));
                ctx[db] = MFMA(pf, b, ctx[db], 0,0,0);
            }
        }
        __syncthreads();
    }
    #pragma unroll
    for (int db = 0; db < 4; ++db)
        #pragma unroll
        for (int r = 0; r < 4; ++r)
            outCb[(size_t)(q0w + d0 + r) * D_K + db * 16 + l15] = ctx[db][r];
    const int kz = ((qhi >> 5) + 1) << 5;
    const f32x4 z = {0.f,0.f,0.f,0.f};
    for (int r = 0; r < 16; ++r) {
        float* rowp = outSb + (size_t)(q0w + r) * S_LEN;
        for (int k = kz + (lane << 2); k < S_LEN; k += 256)
            *(f32x4*)(rowp + k) = z;
    }
}

extern "C" void kernel_launch(void* const* d_in, const int* in_sizes, int n_in,
                              void* d_out, int out_size, void* d_ws, size_t ws_size,
                              hipStream_t stream) {
    const float* Q = (const float*)d_in[0];
    const float* K = (const float*)d_in[1];
    const float* V = (const float*)d_in[2];
    float* outC = (float*)d_out;
    float* outS = (float*)d_out + (size_t)NBH * S_LEN * D_K;

    const size_t kb_elems = (size_t)NBH * S_LEN * D_K;
    const size_t vt_elems = (size_t)NBH * D_K * VT_STRIDE;
    const size_t need = (kb_elems + vt_elems) * sizeof(short);

    if (ws_size >= need) {
        short* Kb = (short*)d_ws;
        short* VT = Kb + kb_elems;
        preconv<<<dim3(NBH * 64), dim3(256), 0, stream>>>(K, V, Kb, VT);
        attn_ss<<<dim3(4096), dim3(256), 0, stream>>>(Q, Kb, VT, outC, outS);
    } else {
        attn_causal_fb<<<dim3(1024), dim3(256), 0, stream>>>(Q, K, V, outC, outS);
    }
}